// Round 2
// baseline (130.932 us; speedup 1.0000x reference)
//
#include <hip/hip_runtime.h>

// input_tensor: [8,128,128,128,1] fp32 ; random_u: [8,8,3] fp32 ; SCALE=0.2
#define NB   8
#define NS   128
#define VOX  (NS*NS*NS)

// Tile 32w x 8h x 8d. Affine coeff bounds (A^T A = 8I closed form):
//   t_diag in [0.8,1.0], |t_offdiag| <= 0.1, |t_trans| <= 0.1.
// Spans: d/h floor-span <= 11 -> 13 staged rows; w cols <= 35 (+3 align) -> ROW_W=40.
// ZERO-BOUNDARY UNIFICATION (R1): unclamped window; boundary blocks zero-fill
// the slab and stage only fully-valid 16B chunks -> one fast compute path.
// PIPELINED PERSISTENT BLOCKS (R2): each block owns the 4 w-tiles of one
// (b,dblk,hblk) row; double-buffered slab; tile t+1's global_load_lds DMA is
// issued right after the loop-top barrier and streams DURING tile t's compute
// (T3 minimum-2-phase pattern; the compiler's vmcnt(0) drain at the next
// barrier lands after the compute phase, so it is cheap).
#define SD    13
#define SH    13
#define ROW_W 40
#define RST   (SH*ROW_W)     // 520
#define SLAB  (SD*RST)       // 6760 floats = 27,040 B; x2 buffers -> 3 blocks/CU

typedef __attribute__((address_space(1))) const void gconst_t;
typedef __attribute__((address_space(3))) void lds_t;

__global__ __launch_bounds__(256) void warp_resample_kernel(
        const float* __restrict__ img, const float* __restrict__ u,
        float* __restrict__ out) {
    __shared__ __align__(16) float slab[2 * SLAB];   // 54,080 B

    const int tid = threadIdx.x;
    // XCD swizzle: 2048 blocks, 8 XCDs -> each XCD = one batch; consecutive
    // blocks on an XCD are consecutive hblk (shared d-plane windows -> L2 hits)
    int bi = blockIdx.x;
    bi = (bi & 7) * 256 + (bi >> 3);               // bijective (2048 % 8 == 0)
    const int hblk = bi & 15;
    const int dblk = (bi >> 4) & 15;
    const int b    = bi >> 8;

    // ---- transform: ALL lanes compute uniformly (Walsh butterfly over the 8
    // corners; the 1/8 of (A^T A)^{-1} = I/8 is folded into the fma constants).
    // No LDS, no barrier: block goes straight to stage-issue. ----
    const float* ub = u + b * 24;
    float T[3][4];
#pragma unroll
    for (int i = 0; i < 3; ++i) {
        float v[8];
#pragma unroll
        for (int n = 0; n < 8; ++n) {
            const float sg = (n & (4 >> i)) ? 1.f : -1.f;
            v[n] = fmaf(sg * 0.025f, ub[n * 3 + i], sg * 0.1f);  // sg*(0.8+0.2u)/8
        }
        const float a0 = v[0] + v[1], a1 = v[2] + v[3];
        const float a2 = v[4] + v[5], a3 = v[6] + v[7];
        const float d0 = v[1] - v[0], d1 = v[3] - v[2];
        const float d2 = v[5] - v[4], d3 = v[7] - v[6];
        const float A01 = a0 + a1, A23 = a2 + a3;
        T[i][0] = A23 - A01;                 // sign of bit2 (mask 4)
        T[i][1] = (a1 - a0) + (a3 - a2);     // sign of bit1 (mask 2)
        T[i][2] = (d0 + d1) + (d2 + d3);     // sign of bit0 (mask 1)
        T[i][3] = A01 + A23;                 // DC (translation column)
    }
    const float t00 = T[0][0], t01 = T[0][1], t02 = T[0][2], t03 = T[0][3];
    const float t10 = T[1][0], t11 = T[1][1], t12 = T[1][2], t13 = T[1][3];
    const float t20 = T[2][0], t21 = T[2][1], t22 = T[2][2], t23 = T[2][3];

    const int d0i = dblk << 3, h0i = hblk << 3;
    const float inv = 2.0f / 127.0f;
    const float x0 = -1.f + d0i * inv, y0 = -1.f + h0i * inv;

    const int wl = tid & 31, hh = tid >> 5;

    // staging lane-task (constant across tiles): LDS float offset = 4*tid, so
    // per-wave dest = di*RST + 256*wave (wave-uniform base + lane*16B, as the
    // global_load_lds hardware requires)
    const int hi     = tid / 10;
    const int cch    = tid - hi * 10;
    const int wvbase = (tid & ~63) << 2;           // floats
    const float* gb  = img + (size_t)b * VOX;

    // per-tile bounds (cur / next register sets)
    int   c_dlo = 0, c_hlo = 0, c_ws = 0, c_Sd = 0, c_Sh = 0, c_allin = 1;
    float c_Pl0 = 0.f, c_Pl1 = 0.f, c_Pl2 = 0.f;
    int   n_dlo = 0, n_hlo = 0, n_ws = 0, n_Sd = 0, n_Sh = 0, n_allin = 1;
    float n_Pl0 = 0.f, n_Pl1 = 0.f, n_Pl2 = 0.f;

    auto bounds = [&](int w0t, int& dlo, int& hlo, int& ws, int& Sdv, int& Shv,
                      int& allin, float& Pl0, float& Pl1, float& Pl2) {
        const float z0 = -1.f + w0t * inv;
        // pixel coords at tile origin; per-index pixel delta == t (inv*63.5 == 1)
        const float P0 = (t00 * x0 + t01 * y0 + t02 * z0 + t03 + 1.f) * 63.5f;
        const float P1 = (t10 * x0 + t11 * y0 + t12 * z0 + t13 + 1.f) * 63.5f;
        const float P2 = (t20 * x0 + t21 * y0 + t22 * z0 + t23 + 1.f) * 63.5f;
        const float mn0 = P0 + fminf(0.f,7.f*t00)+fminf(0.f,7.f*t01)+fminf(0.f,31.f*t02);
        const float mx0 = P0 + fmaxf(0.f,7.f*t00)+fmaxf(0.f,7.f*t01)+fmaxf(0.f,31.f*t02);
        const float mn1 = P1 + fminf(0.f,7.f*t10)+fminf(0.f,7.f*t11)+fminf(0.f,31.f*t12);
        const float mx1 = P1 + fmaxf(0.f,7.f*t10)+fmaxf(0.f,7.f*t11)+fmaxf(0.f,31.f*t12);
        const float mn2 = P2 + fminf(0.f,7.f*t20)+fminf(0.f,7.f*t21)+fminf(0.f,31.f*t22);
        const float mx2 = P2 + fmaxf(0.f,7.f*t20)+fmaxf(0.f,7.f*t21)+fmaxf(0.f,31.f*t22);
        const int i0mn = (int)floorf(mn0), i0mx = (int)floorf(mx0);
        const int i1mn = (int)floorf(mn1), i1mx = (int)floorf(mx1);
        const int i2mn = (int)floorf(mn2), i2mx = (int)floorf(mx2);
        dlo = i0mn;                       // UNCLAMPED window origin
        hlo = i1mn;
        ws  = (i2mn - 1) & ~3;            // 4-aligned floor (works for <0)
        Sdv = min(i0mx + 2 - dlo, SD);
        Shv = min(i1mx + 2 - hlo, SH);
        allin = __builtin_amdgcn_readfirstlane(
            (dlo >= 0 && dlo + Sdv <= NS && hlo >= 0 && hlo + Shv <= NS &&
             ws >= 0 && ws + ROW_W <= NS) ? 1 : 0);
        // local-window coordinates: fold the window origin into the uniform part
        Pl0 = P0 - (float)dlo; Pl1 = P1 - (float)hlo; Pl2 = P2 - (float)ws;
    };

    auto zerofill = [&](int bsel) {
        float4* p = (float4*)(slab + bsel * SLAB);
        for (int i = tid; i < SLAB / 4; i += 256)    // 1690 float4s
            p[i] = make_float4(0.f, 0.f, 0.f, 0.f);
    };

    auto stage = [&](int bsel, int dlo, int hlo, int ws, int Sdv, int Shv,
                     int allin) {
        float* dst0 = slab + bsel * SLAB;
        if (allin) {
            if (hi < Shv) {
                for (int di = 0; di < Sdv; ++di) {
                    const float* g = gb + (((dlo + di) * NS + (hlo + hi)) * NS
                                           + ws + (cch << 2));
                    __builtin_amdgcn_global_load_lds(
                        (gconst_t*)g, (lds_t*)(dst0 + di * RST + wvbase), 16, 0, 0);
                }
            }
        } else {
            // fully-valid 16B chunks only; skipped chunks keep their zeros
            const int  cc = ws + (cch << 2);
            const bool ok = (hi < Shv) && ((unsigned)(hlo + hi) < NS)
                                       && ((unsigned)cc <= NS - 4);
            if (ok) {
                for (int di = 0; di < Sdv; ++di) {
                    if ((unsigned)(dlo + di) < NS) {
                        const float* g = gb + (((dlo + di) * NS + (hlo + hi)) * NS + cc);
                        __builtin_amdgcn_global_load_lds(
                            (gconst_t*)g, (lds_t*)(dst0 + di * RST + wvbase), 16, 0, 0);
                    }
                }
            }
        }
    };

    // ---- prologue: bounds+stage tile 0 into buf0 ----
    bounds(0, c_dlo, c_hlo, c_ws, c_Sd, c_Sh, c_allin, c_Pl0, c_Pl1, c_Pl2);
    if (!c_allin) { zerofill(0); __syncthreads(); }
    stage(0, c_dlo, c_hlo, c_ws, c_Sd, c_Sh, c_allin);

    const size_t ob = (((size_t)(b * NS + d0i) * NS + (h0i + hh)) * NS) + wl;

    for (int t = 0; t < 4; ++t) {
        // loop-top barrier: (a) buf[t&1]'s DMA drained (vmcnt(0) at barrier),
        // (b) all reads of buf[(t+1)&1] from tile t-1 are done -> safe restage
        __syncthreads();

        if (t < 3) {
            bounds((t + 1) << 5, n_dlo, n_hlo, n_ws, n_Sd, n_Sh, n_allin,
                   n_Pl0, n_Pl1, n_Pl2);
            if (!n_allin) { zerofill((t + 1) & 1); __syncthreads(); }
            stage((t + 1) & 1, n_dlo, n_hlo, n_ws, n_Sd, n_Sh, n_allin);
            // prefetch DMA now in flight; it lands during the compute below
        }

        // ---- compute tile t from buf[t&1] (local window coords, one path) ----
        const float* bp = slab + (t & 1) * SLAB;
        float ql0 = c_Pl0 + hh * t01 + wl * t02;
        float ql1 = c_Pl1 + hh * t11 + wl * t12;
        float ql2 = c_Pl2 + hh * t21 + wl * t22;

        float res[8];
#pragma unroll
        for (int k = 0; k < 8; ++k) {
            const float f0 = floorf(ql0), f1 = floorf(ql1), f2 = floorf(ql2);
            const int   i0 = (int)f0,     i1 = (int)f1,     i2 = (int)f2;
            const float r0 = ql0 - f0,    r1 = ql1 - f1,    r2 = ql2 - f2;

            const int base = i0 * RST + i1 * ROW_W + i2;      // const strides
            float a00 = bp[base],           b00 = bp[base + 1];
            float a01 = bp[base + ROW_W],   b01 = bp[base + ROW_W + 1];
            const int base2 = base + RST;
            float a10 = bp[base2],          b10 = bp[base2 + 1];
            float a11 = bp[base2 + ROW_W],  b11 = bp[base2 + ROW_W + 1];

            float e0 = fmaf(r2, b00 - a00, a00);
            float e1 = fmaf(r2, b01 - a01, a01);
            float e2 = fmaf(r2, b10 - a10, a10);
            float e3 = fmaf(r2, b11 - a11, a11);
            float c0 = fmaf(r1, e1 - e0, e0);
            float c1 = fmaf(r1, e3 - e2, e2);
            res[k] = fmaf(r0, c1 - c0, c0);

            ql0 += t00; ql1 += t10; ql2 += t20;
        }

        // stores: wave = 2 h-rows x 32 consecutive w -> coalesced 128B segments
        const size_t obt = ob + (size_t)(t << 5);
#pragma unroll
        for (int k = 0; k < 8; ++k)
            out[obt + (size_t)k * NS * NS] = res[k];

        // rotate next -> cur
        c_dlo = n_dlo; c_hlo = n_hlo; c_ws = n_ws; c_Sd = n_Sd; c_Sh = n_Sh;
        c_allin = n_allin; c_Pl0 = n_Pl0; c_Pl1 = n_Pl1; c_Pl2 = n_Pl2;
    }
}

extern "C" void kernel_launch(void* const* d_in, const int* in_sizes, int n_in,
                              void* d_out, int out_size, void* d_ws, size_t ws_size,
                              hipStream_t stream) {
    const float* img = (const float*)d_in[0];   // [8,128,128,128,1] fp32
    const float* u   = (const float*)d_in[1];   // [8,8,3] fp32
    float* out = (float*)d_out;

    int blocks = NB * 16 * 16;                  // 2048 blocks x 4 w-tiles each
    warp_resample_kernel<<<blocks, 256, 0, stream>>>(img, u, out);
}

// Round 3
// 122.053 us; speedup vs baseline: 1.0728x; 1.0728x over previous
//
#include <hip/hip_runtime.h>

// input_tensor: [8,128,128,128,1] fp32 ; random_u: [8,8,3] fp32 ; SCALE=0.2
#define NB   8
#define NS   128
#define VOX  (NS*NS*NS)

// Tile 32w x 8h x 8d. Affine coeff bounds (A^T A = 8I closed form):
//   t_diag in [0.8,1.0], |t_offdiag| <= 0.1, |t_trans| <= 0.1.
// Spans: d/h floor-span <= 11 -> 13 staged rows; w cols <= 35 (+align) -> ROW_W=40.
// ZERO-BOUNDARY UNIFICATION (R1): unclamped window; boundary blocks zero-fill
// the slab and stage only fully-valid 16B chunks -> one fast compute path.
// R3 = R1 structure (single slab, 27 KB, 6 blocks/CU, 8192 blocks — occupancy
// is the binding resource, proven by R2's regression) + R2's verified pieces:
//   * XCD swizzle: b = bi&7 -> each XCD-private 4MB L2 serves ONE batch; a
//     fixed (b,dblk) slab is 13 planes = 851 KB -> staging is L2-hit, which
//     shortens the per-block stage->drain latency (the actual bottleneck).
//   * barrier-free uniform transform (Walsh butterfly, all 64 lanes).
//   * local-window coordinates (window origin folded into the uniform part).
#define SD    13
#define SH    13
#define ROW_W 40
#define RST   (SH*ROW_W)     // 520
#define SLAB  (SD*RST)       // 6760 floats = 27,040 B -> 6 blocks/CU

typedef __attribute__((address_space(1))) const void gconst_t;
typedef __attribute__((address_space(3))) void lds_t;

__global__ __launch_bounds__(256) void warp_resample_kernel(
        const float* __restrict__ img, const float* __restrict__ u,
        float* __restrict__ out) {
    __shared__ __align__(16) float slab[SLAB];

    const int tid = threadIdx.x;
    // XCD swizzle: consecutive blockIdx round-robin across the 8 XCDs, so
    // b = bi&7 pins each batch to one XCD; within an XCD, idx sweeps
    // w-tiles then h-tiles of the same d-slab -> window overlap stays in L2.
    const int bi   = blockIdx.x;
    const int b    =  bi & 7;
    const int idx  =  bi >> 3;
    const int wblk =  idx & 3;          // 4 w-tiles of 32
    const int hblk = (idx >> 2) & 15;   // 16 h-tiles of 8
    const int dblk =  idx >> 6;         // 16 d-tiles of 8

    // ---- transform: ALL lanes compute uniformly (Walsh butterfly over the 8
    // corners; the 1/8 of (A^T A)^{-1} = I/8 folded into the fma constants).
    // No LDS, no barrier. (Verified in R2.) ----
    const float* ub = u + b * 24;
    float T[3][4];
#pragma unroll
    for (int i = 0; i < 3; ++i) {
        float v[8];
#pragma unroll
        for (int n = 0; n < 8; ++n) {
            const float sg = (n & (4 >> i)) ? 1.f : -1.f;
            v[n] = fmaf(sg * 0.025f, ub[n * 3 + i], sg * 0.1f);  // sg*(0.8+0.2u)/8
        }
        const float a0 = v[0] + v[1], a1 = v[2] + v[3];
        const float a2 = v[4] + v[5], a3 = v[6] + v[7];
        const float d0 = v[1] - v[0], d1 = v[3] - v[2];
        const float d2 = v[5] - v[4], d3 = v[7] - v[6];
        const float A01 = a0 + a1, A23 = a2 + a3;
        T[i][0] = A23 - A01;                 // sign of bit2 (mask 4)
        T[i][1] = (a1 - a0) + (a3 - a2);     // sign of bit1 (mask 2)
        T[i][2] = (d0 + d1) + (d2 + d3);     // sign of bit0 (mask 1)
        T[i][3] = A01 + A23;                 // DC (translation column)
    }
    const float t00 = T[0][0], t01 = T[0][1], t02 = T[0][2], t03 = T[0][3];
    const float t10 = T[1][0], t11 = T[1][1], t12 = T[1][2], t13 = T[1][3];
    const float t20 = T[2][0], t21 = T[2][1], t22 = T[2][2], t23 = T[2][3];

    const int d0i = dblk << 3, h0i = hblk << 3, w0i = wblk << 5;
    const float inv = 2.0f / 127.0f;
    const float x0 = -1.f + d0i * inv, y0 = -1.f + h0i * inv, z0 = -1.f + w0i * inv;
    // pixel coords at tile origin; per-index pixel delta == t (inv*63.5 == 1)
    const float P0 = (t00 * x0 + t01 * y0 + t02 * z0 + t03 + 1.f) * 63.5f;
    const float P1 = (t10 * x0 + t11 * y0 + t12 * z0 + t13 + 1.f) * 63.5f;
    const float P2 = (t20 * x0 + t21 * y0 + t22 * z0 + t23 + 1.f) * 63.5f;

    // tile bounds via corner extremes (kd<=7, kh<=7, kw<=31)
    const float mn0 = P0 + fminf(0.f,7.f*t00)+fminf(0.f,7.f*t01)+fminf(0.f,31.f*t02);
    const float mx0 = P0 + fmaxf(0.f,7.f*t00)+fmaxf(0.f,7.f*t01)+fmaxf(0.f,31.f*t02);
    const float mn1 = P1 + fminf(0.f,7.f*t10)+fminf(0.f,7.f*t11)+fminf(0.f,31.f*t12);
    const float mx1 = P1 + fmaxf(0.f,7.f*t10)+fmaxf(0.f,7.f*t11)+fmaxf(0.f,31.f*t12);
    const float mn2 = P2 + fminf(0.f,7.f*t20)+fminf(0.f,7.f*t21)+fminf(0.f,31.f*t22);
    const float mx2 = P2 + fmaxf(0.f,7.f*t20)+fmaxf(0.f,7.f*t21)+fmaxf(0.f,31.f*t22);

    const int i0mn = (int)floorf(mn0), i0mx = (int)floorf(mx0);
    const int i1mn = (int)floorf(mn1), i1mx = (int)floorf(mx1);
    const int i2mn = (int)floorf(mn2), i2mx = (int)floorf(mx2);

    // UNCLAMPED window origin (may be negative / past the image)
    const int d_lo = i0mn;
    const int h_lo = i1mn;
    const int ws   = (i2mn - 1) & ~3;          // 4-aligned floor (works for <0)
    const int Sd   = min(i0mx + 2 - d_lo, SD); // staged d-planes <= 13
    const int Sh   = min(i1mx + 2 - h_lo, SH);

    // block-uniform: is the whole staged window inside the image?
    const int allin = __builtin_amdgcn_readfirstlane(
        (d_lo >= 0 && d_lo + Sd <= NS &&
         h_lo >= 0 && h_lo + Sh <= NS &&
         ws   >= 0 && ws + ROW_W <= NS) ? 1 : 0);

    // local-window coordinates (fold window origin into the uniform part)
    const float Pl0 = P0 - (float)d_lo;
    const float Pl1 = P1 - (float)h_lo;
    const float Pl2 = P2 - (float)ws;

    // ---- boundary blocks only: zero-fill slab so OOB taps read 0.0 ----
    if (!allin) {
        float4* p = (float4*)slab;
        for (int i = tid; i < SLAB / 4; i += 256)   // 1690 float4s
            p[i] = make_float4(0.f, 0.f, 0.f, 0.f);
        __syncthreads();   // zeros visible before any LDS-DMA write can land
    }

    // ---- stage slab: Sd*Sh rows of ROW_W floats via global_load_lds x16 ----
    // lane-task: hi = tid/10, chunk = tid%10; LDS float offset = 4*tid exactly,
    // so per-wave LDS base = di*RST + 256*wave (wave-uniform base + lane*16B).
    {
        const float* gb = img + (size_t)b * VOX;
        const int hi = tid / 10;
        const int c  = tid - hi * 10;
        const int wvbase = (tid & ~63) << 2;                  // floats
        if (allin) {
            if (hi < Sh) {
                for (int di = 0; di < Sd; ++di) {
                    const float* g = gb + (((d_lo + di) * NS + (h_lo + hi)) * NS
                                           + ws + (c << 2));
                    __builtin_amdgcn_global_load_lds(
                        (gconst_t*)g, (lds_t*)(slab + di * RST + wvbase), 16, 0, 0);
                }
            }
        } else {
            // fully-valid 16B chunks only; skipped chunks keep their zeros
            const int  cc = ws + (c << 2);
            const bool ok = (hi < Sh) && ((unsigned)(h_lo + hi) < NS)
                                      && ((unsigned)cc <= NS - 4);
            if (ok) {
                for (int di = 0; di < Sd; ++di) {
                    if ((unsigned)(d_lo + di) < NS) {
                        const float* g = gb + (((d_lo + di) * NS + (h_lo + hi)) * NS
                                               + cc);
                        __builtin_amdgcn_global_load_lds(
                            (gconst_t*)g, (lds_t*)(slab + di * RST + wvbase), 16, 0, 0);
                    }
                }
            }
        }
    }
    __syncthreads();

    // ---- unified compute: lanes dense along w; 8 voxels along d per thread ----
    // floorf (not (int)cast) so coords floor correctly near 0; every tap's
    // LOCAL index is in-window by the span analysis; OOB-image slots read 0.
    const int wl = tid & 31, hh = tid >> 5;
    float ql0 = Pl0 + hh * t01 + wl * t02;
    float ql1 = Pl1 + hh * t11 + wl * t12;
    float ql2 = Pl2 + hh * t21 + wl * t22;

    float res[8];
#pragma unroll
    for (int k = 0; k < 8; ++k) {
        const float f0 = floorf(ql0), f1 = floorf(ql1), f2 = floorf(ql2);
        const int   i0 = (int)f0,     i1 = (int)f1,     i2 = (int)f2;
        const float r0 = ql0 - f0,    r1 = ql1 - f1,    r2 = ql2 - f2;

        const int base = i0 * RST + i1 * ROW_W + i2;      // const strides
        float a00 = slab[base],           b00 = slab[base + 1];
        float a01 = slab[base + ROW_W],   b01 = slab[base + ROW_W + 1];
        const int base2 = base + RST;
        float a10 = slab[base2],          b10 = slab[base2 + 1];
        float a11 = slab[base2 + ROW_W],  b11 = slab[base2 + ROW_W + 1];

        float e0 = fmaf(r2, b00 - a00, a00);
        float e1 = fmaf(r2, b01 - a01, a01);
        float e2 = fmaf(r2, b10 - a10, a10);
        float e3 = fmaf(r2, b11 - a11, a11);
        float c0 = fmaf(r1, e1 - e0, e0);
        float c1 = fmaf(r1, e3 - e2, e2);
        res[k] = fmaf(r0, c1 - c0, c0);

        ql0 += t00; ql1 += t10; ql2 += t20;
    }

    // stores: wave = 2 h-rows x 32 consecutive w -> coalesced 128B segments
    size_t ob = (((size_t)(b * NS + d0i) * NS + (h0i + hh)) * NS) + w0i + wl;
#pragma unroll
    for (int k = 0; k < 8; ++k)
        out[ob + (size_t)k * NS * NS] = res[k];
}

extern "C" void kernel_launch(void* const* d_in, const int* in_sizes, int n_in,
                              void* d_out, int out_size, void* d_ws, size_t ws_size,
                              hipStream_t stream) {
    const float* img = (const float*)d_in[0];   // [8,128,128,128,1] fp32
    const float* u   = (const float*)d_in[1];   // [8,8,3] fp32
    float* out = (float*)d_out;

    int blocks = NB * 16 * 16 * 4;              // 8192 (b=xcd x 16d x 16h x 4w)
    warp_resample_kernel<<<blocks, 256, 0, stream>>>(img, u, out);
}